// Round 7
// baseline (2200.151 us; speedup 1.0000x reference)
//
#include <hip/hip_runtime.h>
#include <hip/hip_bf16.h>

// EMD via Sinkhorn (EPS=0.02, 50 iters), B=16, N=M=2048, 3-D points.
// Potentials in base-2 log domain scaled by 1/EPS:
//   u2 = (f/EPS)*log2(e), v2 = (g/EPS)*log2(e)
// Half-iteration with per-row static shift c[n] = KSCALE*dmin[n]:
//   u2[n] = -log2(N) + c[n] - log2( sum_m 2^(v2[m] - d(n,m)*KSCALE + c[n]) )
// Shift guarantees max term >= 2^(v[nn]) (no underflow), computed once.
// Loss: (1/B) * sum_{b,n,m} 2^(u2[n]+v2[m]-d*KSCALE) * d
//
// R1: LDS-BW theory -> 4 rows/thread: no change (not LDS-bound).
// R3: plain sum NaN'd (full-row underflow for isolated rows).
// R4: dmin shift + v_pk_fma_f32 math: 2859 -> 2175 us (21.3 us/half-step).
// R5: launch_bounds(256,8) forced VGPR 52->32 -> spills -> 4063 us.
// R6: CHUNK=1024 LDS headroom: NO change -- grid (1024 blocks) caps us at
//     4 blocks/CU anyway. Occupancy never actually rose.
// R7: grid 2048 (RPB=16, RPT=2): true 8 blocks/CU (grid, LDS=20KB, and
//     VGPR<=64 all allow it). Inner math identical, packed fmax.

#define BATCH 16
#define NPTS 2048
#define RPB 16           // rows per block
#define RPT 2            // rows per thread (one float2 pair)
#define KU 4             // column unroll per J-iteration
#define CHUNK 1024       // columns staged per chunk (16+4 KB LDS)
#define KSCALE 72.13475204444817f   // (1/0.02) * log2(e)
#define NEG_LOG2N (-11.0f)          // -log2(2048)

typedef float v2f __attribute__((ext_vector_type(2)));

#if __has_builtin(__builtin_amdgcn_exp2f)
#define EX2(x) __builtin_amdgcn_exp2f(x)
#else
#define EX2(x) exp2f(x)
#endif
#if __has_builtin(__builtin_amdgcn_logf)
#define LG2(x) __builtin_amdgcn_logf(x)
#else
#define LG2(x) log2f(x)
#endif
#if __has_builtin(__builtin_amdgcn_sqrtf)
#define SQRTF(x) __builtin_amdgcn_sqrtf(x)
#else
#define SQRTF(x) sqrtf(x)
#endif
#define VMIN(a, b) __builtin_elementwise_min(a, b)
#define VMAX(a, b) __builtin_elementwise_max(a, b)

__global__ __launch_bounds__(256) void prep_kernel(
    const float* __restrict__ tpl, const float* __restrict__ src,
    float4* __restrict__ Xp, float4* __restrict__ Yp, float* __restrict__ v2) {
  int i = blockIdx.x * 256 + threadIdx.x;
  if (i < BATCH * NPTS) {
    float x0 = tpl[3*i], x1 = tpl[3*i+1], x2 = tpl[3*i+2];
    Xp[i] = make_float4(x0, x1, x2, x0*x0 + x1*x1 + x2*x2);
    float y0 = src[3*i], y1 = src[3*i+1], y2 = src[3*i+2];
    Yp[i] = make_float4(y0, y1, y2, y0*y0 + y1*y1 + y2*y2);
    v2[i] = 0.0f;
  }
}

// Pre-pass: cshift[n] = KSCALE * min_m d(n,m). Grid 1024, RPB'=32, RPT'=4.
__global__ __launch_bounds__(256, 4) void dmin_kernel(
    const float4* __restrict__ Rp, const float4* __restrict__ Cp,
    float* __restrict__ cshift) {
  __shared__ float4 sY[NPTS];   // 32 KB
  int bx = blockIdx.x;
  int b = bx >> 6;
  int rblk = bx & 63;
  int tid = threadIdx.x;
  const float4* cb = Cp + b * NPTS;
  for (int i = tid; i < NPTS; i += 256) sY[i] = cb[i];
  __syncthreads();

  int rg = tid >> 5, lane = tid & 31;
  int nbase = rblk * 32 + rg * 4;

  v2f xx[2], xy[2], xz[2], xw[2], msq[2];
#pragma unroll
  for (int p = 0; p < 2; ++p) {
    float4 a = Rp[b * NPTS + nbase + 2*p];
    float4 c = Rp[b * NPTS + nbase + 2*p + 1];
    xx[p] = (v2f){a.x, c.x}; xy[p] = (v2f){a.y, c.y};
    xz[p] = (v2f){a.z, c.z}; xw[p] = (v2f){a.w, c.w};
    msq[p] = (v2f){1e30f, 1e30f};
  }

  for (int J = 0; J < NPTS / (32 * KU); ++J) {
    float4 yp[KU];
#pragma unroll
    for (int k = 0; k < KU; ++k) yp[k] = sY[J * (32 * KU) + k * 32 + lane];
#pragma unroll
    for (int k = 0; k < KU; ++k) {
#pragma unroll
      for (int p = 0; p < 2; ++p) {
        v2f dot = xx[p] * yp[k].x;
        dot = xy[p] * yp[k].y + dot;
        dot = xz[p] * yp[k].z + dot;
        v2f sq = xw[p] + yp[k].w;
        sq = dot * (-2.0f) + sq;
        msq[p] = VMIN(msq[p], sq);
      }
    }
  }
  float s[4] = { msq[0].x, msq[0].y, msq[1].x, msq[1].y };
#pragma unroll
  for (int off = 1; off < 32; off <<= 1) {
#pragma unroll
    for (int r = 0; r < 4; ++r) s[r] = fminf(s[r], __shfl_xor(s[r], off));
  }
  if (lane == 0) {
#pragma unroll
    for (int r = 0; r < 4; ++r)
      cshift[b * NPTS + nbase + r] = KSCALE * SQRTF(fmaxf(s[r], 1e-12f));
  }
}

// One Sinkhorn half-step for 16 rows of batch b, column tiles of 1024:
//   wout[n] = -log2(N) + c[n] - log2( sum_m 2^(win[m] - d(n,m)*KSCALE + c[n]) )
// Symmetric: (Xp,Yp,v2,cX,u2) for f-update, (Yp,Xp,u2,cY,v2) for g-update.
__global__ __launch_bounds__(256, 8) void sink_half(
    const float4* __restrict__ Rp,   // points whose potentials we update
    const float4* __restrict__ Cp,   // points scanned (columns)
    const float* __restrict__ win,   // incoming potential (base-2, scaled)
    const float* __restrict__ crow,  // per-row shift KSCALE*dmin
    float* __restrict__ wout) {
  __shared__ float4 sY[CHUNK];   // 16 KB
  __shared__ float  sv[CHUNK];   // 4 KB
  int bx = blockIdx.x;
  int b = bx >> 7;              // 128 row-blocks per batch
  int rblk = bx & 127;
  int tid = threadIdx.x;
  const float4* cb = Cp + b * NPTS;
  const float*  vb = win + b * NPTS;

  int rg = tid >> 5, lane = tid & 31;    // 8 row-groups x 32 lanes
  int nbase = rblk * RPB + rg * RPT;

  float4 a0 = Rp[b * NPTS + nbase];
  float4 a1 = Rp[b * NPTS + nbase + 1];
  v2f xx = (v2f){a0.x, a1.x}, xy = (v2f){a0.y, a1.y};
  v2f xz = (v2f){a0.z, a1.z}, xw = (v2f){a0.w, a1.w};
  v2f csh = (v2f){crow[b * NPTS + nbase], crow[b * NPTS + nbase + 1]};
  v2f acc = (v2f){0.0f, 0.0f};
  const v2f sqfloor = (v2f){1e-12f, 1e-12f};

  for (int cch = 0; cch < NPTS / CHUNK; ++cch) {   // 2 column chunks
    if (cch) __syncthreads();                      // protect previous reads
#pragma unroll
    for (int i = 0; i < CHUNK / 256; ++i) {
      sY[tid + i * 256] = cb[cch * CHUNK + tid + i * 256];
      sv[tid + i * 256] = vb[cch * CHUNK + tid + i * 256];
    }
    __syncthreads();

    for (int J = 0; J < CHUNK / (32 * KU); ++J) {  // 8 iterations
      float4 yp[KU];
      float  vm[KU];
#pragma unroll
      for (int k = 0; k < KU; ++k) {
        int m = J * (32 * KU) + k * 32 + lane;
        yp[k] = sY[m];
        vm[k] = sv[m];
      }
#pragma unroll
      for (int k = 0; k < KU; ++k) {
        v2f dot = xx * yp[k].x;
        dot = xy * yp[k].y + dot;
        dot = xz * yp[k].z + dot;
        v2f sq = xw + yp[k].w;
        sq = dot * (-2.0f) + sq;
        sq = VMAX(sq, sqfloor);
        float d0 = SQRTF(sq.x);
        float d1 = SQRTF(sq.y);
        v2f arg = (v2f){d0, d1} * (-KSCALE) + (csh + vm[k]);
        acc += (v2f){EX2(arg.x), EX2(arg.y)};
      }
    }
  }

  float s0 = acc.x, s1 = acc.y;
#pragma unroll
  for (int off = 1; off < 32; off <<= 1) {
    s0 += __shfl_xor(s0, off);
    s1 += __shfl_xor(s1, off);
  }
  if (lane == 0) {
    wout[b * NPTS + nbase]     = NEG_LOG2N + csh.x - LG2(s0);
    wout[b * NPTS + nbase + 1] = NEG_LOG2N + csh.y - LG2(s1);
  }
}

// Final pass: partial[block] = sum over this block's 32 rows of sum_m 2^(u2+v2-d*K)*d
__global__ __launch_bounds__(256, 4) void final_kernel(
    const float4* __restrict__ Xp, const float4* __restrict__ Yp,
    const float* __restrict__ u2, const float* __restrict__ v2,
    float* __restrict__ partials) {
  __shared__ float4 sY[NPTS];   // 32 KB
  __shared__ float  sv[NPTS];   // 8 KB
  __shared__ float  red[8];
  int bx = blockIdx.x;
  int b = bx >> 6;
  int rblk = bx & 63;
  int tid = threadIdx.x;
  const float4* cb = Yp + b * NPTS;
  const float*  vb = v2 + b * NPTS;
  for (int i = tid; i < NPTS; i += 256) { sY[i] = cb[i]; sv[i] = vb[i]; }
  __syncthreads();

  int rg = tid >> 5, lane = tid & 31;
  int nbase = rblk * 32 + rg * 4;

  float4 xp[4];
  float un[4], acc[4];
#pragma unroll
  for (int r = 0; r < 4; ++r) {
    xp[r] = Xp[b * NPTS + nbase + r];
    un[r] = u2[b * NPTS + nbase + r];
    acc[r] = 0.0f;
  }

  for (int J = 0; J < NPTS / (32 * KU); ++J) {
    float4 yp[KU];
    float  vm[KU];
#pragma unroll
    for (int k = 0; k < KU; ++k) {
      int m = J * (32 * KU) + k * 32 + lane;
      yp[k] = sY[m];
      vm[k] = sv[m];
    }
#pragma unroll
    for (int k = 0; k < KU; ++k) {
#pragma unroll
      for (int r = 0; r < 4; ++r) {
        float dot = fmaf(xp[r].z, yp[k].z, fmaf(xp[r].y, yp[k].y, xp[r].x * yp[k].x));
        float sq  = fmaf(-2.0f, dot, xp[r].w + yp[k].w);
        float d   = SQRTF(fmaxf(sq, 1e-12f));
        float e   = EX2(fmaf(d, -KSCALE, un[r] + vm[k]));
        acc[r] = fmaf(e, d, acc[r]);
      }
    }
  }
  float a = (acc[0] + acc[1]) + (acc[2] + acc[3]);
#pragma unroll
  for (int off = 1; off < 32; off <<= 1) a += __shfl_xor(a, off);
  if (lane == 0) red[rg] = a;
  __syncthreads();
  if (tid == 0) {
    float sblk = 0.0f;
#pragma unroll
    for (int i = 0; i < 8; ++i) sblk += red[i];
    partials[bx] = sblk;
  }
}

__global__ __launch_bounds__(256) void reduce_kernel(
    const float* __restrict__ partials, float* __restrict__ out) {
  __shared__ float red[4];
  int tid = threadIdx.x;
  float a = (partials[tid] + partials[tid + 256]) +
            (partials[tid + 512] + partials[tid + 768]);
#pragma unroll
  for (int off = 1; off < 64; off <<= 1) a += __shfl_xor(a, off);
  if ((tid & 63) == 0) red[tid >> 6] = a;
  __syncthreads();
  if (tid == 0) out[0] = ((red[0] + red[1]) + (red[2] + red[3])) * (1.0f / BATCH);
}

extern "C" void kernel_launch(void* const* d_in, const int* in_sizes, int n_in,
                              void* d_out, int out_size, void* d_ws, size_t ws_size,
                              hipStream_t stream) {
  const float* tpl = (const float*)d_in[0];
  const float* src = (const float*)d_in[1];
  float* out = (float*)d_out;
  char* ws = (char*)d_ws;

  const size_t ptsBytes = (size_t)BATCH * NPTS * sizeof(float4);   // 512 KB
  const size_t potBytes = (size_t)BATCH * NPTS * sizeof(float);    // 128 KB
  float4* Xp = (float4*)ws;
  float4* Yp = (float4*)(ws + ptsBytes);
  float*  u2 = (float*)(ws + 2 * ptsBytes);
  float*  v2 = (float*)(ws + 2 * ptsBytes + potBytes);
  float*  cX = (float*)(ws + 2 * ptsBytes + 2 * potBytes);
  float*  cY = (float*)(ws + 2 * ptsBytes + 3 * potBytes);
  float*  partials = (float*)(ws + 2 * ptsBytes + 4 * potBytes);   // 4 KB

  prep_kernel<<<(BATCH * NPTS + 255) / 256, 256, 0, stream>>>(tpl, src, Xp, Yp, v2);
  dmin_kernel<<<BATCH * 64, 256, 0, stream>>>(Xp, Yp, cX);
  dmin_kernel<<<BATCH * 64, 256, 0, stream>>>(Yp, Xp, cY);
  for (int it = 0; it < 50; ++it) {
    sink_half<<<BATCH * 128, 256, 0, stream>>>(Xp, Yp, v2, cX, u2);   // f-update
    sink_half<<<BATCH * 128, 256, 0, stream>>>(Yp, Xp, u2, cY, v2);   // g-update
  }
  final_kernel<<<BATCH * 64, 256, 0, stream>>>(Xp, Yp, u2, v2, partials);
  reduce_kernel<<<1, 256, 0, stream>>>(partials, out);
}

// Round 8
// 2189.429 us; speedup vs baseline: 1.0049x; 1.0049x over previous
//
#include <hip/hip_runtime.h>
#include <hip/hip_bf16.h>

// EMD via Sinkhorn (EPS=0.02, 50 iters), B=16, N=M=2048, 3-D points.
// Potentials in base-2 log domain scaled by 1/EPS (u2 = f/EPS*log2e).
//
// R8 structural change: the kernel matrix is ITERATION-INVARIANT. Precompute
//   q''(n,m) = 2^((c_n+e_m)/2 - K*d(n,m))   (bf16, 128 MB per direction)
// with c = K*dmin_row, e = K*dmin_col. Every entry in [0,1]; every row and
// column keeps its nearest-neighbor entry >= 2^-36 -> no underflow/NaN.
// Each half-step is then a pure streaming GEMV (no sqrt, no exp2 per elem):
//   S_n = sum_m q''(n,m) * w_m,  w_m = 2^(v_m - e_m/2)  (staged, 1 exp2/row)
//   u_n = -log2N + c_n/2 - log2(S_n);  z_n = 2^(u_n - c_n/2) staged for next.
// Last v-update uses the exact fp32 kernel so final column marginals are
// fp32-exact. Falls back to the proven R7 path if ws_size < ~258 MB.
//
// History: R4 dmin-shift+pk-math 2859->2175us; R5 spill regression; R6/R7
// occupancy levers: no change (trans-issue-bound at ~21us/half-step).

#define BATCH 16
#define NPTS 2048
#define RPB 16           // rows per block (exact sink_half)
#define RPT 2
#define KU 4
#define CHUNK 1024
#define KSCALE 72.13475204444817f   // (1/0.02) * log2(e)
#define NEG_LOG2N (-11.0f)          // -log2(2048)

typedef float v2f __attribute__((ext_vector_type(2)));

#if __has_builtin(__builtin_amdgcn_exp2f)
#define EX2(x) __builtin_amdgcn_exp2f(x)
#else
#define EX2(x) exp2f(x)
#endif
#if __has_builtin(__builtin_amdgcn_logf)
#define LG2(x) __builtin_amdgcn_logf(x)
#else
#define LG2(x) log2f(x)
#endif
#if __has_builtin(__builtin_amdgcn_sqrtf)
#define SQRTF(x) __builtin_amdgcn_sqrtf(x)
#else
#define SQRTF(x) sqrtf(x)
#endif
#define VMIN(a, b) __builtin_elementwise_min(a, b)
#define VMAX(a, b) __builtin_elementwise_max(a, b)

__global__ __launch_bounds__(256) void prep_kernel(
    const float* __restrict__ tpl, const float* __restrict__ src,
    float4* __restrict__ Xp, float4* __restrict__ Yp, float* __restrict__ v2) {
  int i = blockIdx.x * 256 + threadIdx.x;
  if (i < BATCH * NPTS) {
    float x0 = tpl[3*i], x1 = tpl[3*i+1], x2 = tpl[3*i+2];
    Xp[i] = make_float4(x0, x1, x2, x0*x0 + x1*x1 + x2*x2);
    float y0 = src[3*i], y1 = src[3*i+1], y2 = src[3*i+2];
    Yp[i] = make_float4(y0, y1, y2, y0*y0 + y1*y1 + y2*y2);
    v2[i] = 0.0f;
  }
}

// cshift[n] = KSCALE*min_m d(n,m); wst[n] = 2^(-cshift/2) (stage for v=0 init)
__global__ __launch_bounds__(256, 4) void dmin_kernel(
    const float4* __restrict__ Rp, const float4* __restrict__ Cp,
    float* __restrict__ cshift, float* __restrict__ wst) {
  __shared__ float4 sY[NPTS];   // 32 KB
  int bx = blockIdx.x;
  int b = bx >> 6;
  int rblk = bx & 63;
  int tid = threadIdx.x;
  const float4* cb = Cp + b * NPTS;
  for (int i = tid; i < NPTS; i += 256) sY[i] = cb[i];
  __syncthreads();

  int rg = tid >> 5, lane = tid & 31;
  int nbase = rblk * 32 + rg * 4;

  v2f xx[2], xy[2], xz[2], xw[2], msq[2];
#pragma unroll
  for (int p = 0; p < 2; ++p) {
    float4 a = Rp[b * NPTS + nbase + 2*p];
    float4 c = Rp[b * NPTS + nbase + 2*p + 1];
    xx[p] = (v2f){a.x, c.x}; xy[p] = (v2f){a.y, c.y};
    xz[p] = (v2f){a.z, c.z}; xw[p] = (v2f){a.w, c.w};
    msq[p] = (v2f){1e30f, 1e30f};
  }

  for (int J = 0; J < NPTS / (32 * KU); ++J) {
    float4 yp[KU];
#pragma unroll
    for (int k = 0; k < KU; ++k) yp[k] = sY[J * (32 * KU) + k * 32 + lane];
#pragma unroll
    for (int k = 0; k < KU; ++k) {
#pragma unroll
      for (int p = 0; p < 2; ++p) {
        v2f dot = xx[p] * yp[k].x;
        dot = xy[p] * yp[k].y + dot;
        dot = xz[p] * yp[k].z + dot;
        v2f sq = xw[p] + yp[k].w;
        sq = dot * (-2.0f) + sq;
        msq[p] = VMIN(msq[p], sq);
      }
    }
  }
  float s[4] = { msq[0].x, msq[0].y, msq[1].x, msq[1].y };
#pragma unroll
  for (int off = 1; off < 32; off <<= 1) {
#pragma unroll
    for (int r = 0; r < 4; ++r) s[r] = fminf(s[r], __shfl_xor(s[r], off));
  }
  if (lane == 0) {
#pragma unroll
    for (int r = 0; r < 4; ++r) {
      float c = KSCALE * SQRTF(fmaxf(s[r], 1e-12f));
      cshift[b * NPTS + nbase + r] = c;
      wst[b * NPTS + nbase + r] = EX2(-0.5f * c);
    }
  }
}

// Precompute q''(n,m) = 2^((c_n+e_m)/2 - K*d(n,m)) as bf16, row-major.
__global__ __launch_bounds__(256) void qgen_kernel(
    const float4* __restrict__ Rp, const float4* __restrict__ Cp,
    const float* __restrict__ crow, const float* __restrict__ ccol,
    unsigned short* __restrict__ Qout) {
  int bx = blockIdx.x;             // 4096 = 16 batches * 256 slabs
  int b = bx >> 8, slab = bx & 255;
  int wave = threadIdx.x >> 6, lane = threadIdx.x & 63;
  const float4* cb = Cp + b * NPTS;
  const float*  eb = ccol + b * NPTS;
  for (int rr = 0; rr < 2; ++rr) {
    int n = slab * 8 + wave * 2 + rr;
    float4 xp = Rp[b * NPTS + n];
    float cr = crow[b * NPTS + n];
    unsigned short* qrow = Qout + ((size_t)(b * NPTS + n)) * NPTS;
#pragma unroll
    for (int seg = 0; seg < 4; ++seg) {
      int c0 = seg * 512 + lane * 8;
      unsigned dw[4];
#pragma unroll
      for (int h = 0; h < 4; ++h) {
        unsigned short qq[2];
#pragma unroll
        for (int j = 0; j < 2; ++j) {
          int m = c0 + 2*h + j;
          float4 yp = cb[m];
          float dot = fmaf(xp.z, yp.z, fmaf(xp.y, yp.y, xp.x * yp.x));
          float sq  = fmaf(-2.0f, dot, xp.w + yp.w);
          float d   = SQRTF(fmaxf(sq, 1e-12f));
          float arg = fmaf(d, -KSCALE, 0.5f * (cr + eb[m]));
          float q   = EX2(arg);
          unsigned bits = __float_as_uint(q);
          qq[j] = (unsigned short)((bits + 0x7FFFu + ((bits >> 16) & 1u)) >> 16);
        }
        dw[h] = (unsigned)qq[0] | ((unsigned)qq[1] << 16);
      }
      *(int4*)(qrow + c0) = make_int4(dw[0], dw[1], dw[2], dw[3]);
    }
  }
}

// Streaming GEMV half-step: S_n = sum_m q''(n,m)*instage_m;
// outpot_n = -log2N + shift_n/2 - log2(S_n); outstage_n = 2^(outpot - shift/2).
__global__ __launch_bounds__(256) void gemv_kernel(
    const unsigned short* __restrict__ Q, const float* __restrict__ instage,
    const float* __restrict__ shift, float* __restrict__ outpot,
    float* __restrict__ outstage) {
  int bx = blockIdx.x;             // 4096
  int b = bx >> 8, slab = bx & 255;
  int wave = threadIdx.x >> 6, lane = threadIdx.x & 63;
  const float* wb = instage + b * NPTS;
  for (int rr = 0; rr < 2; ++rr) {
    int n = slab * 8 + wave * 2 + rr;
    const int4* qrow = (const int4*)(Q + ((size_t)(b * NPTS + n)) * NPTS);
    v2f acc = (v2f){0.0f, 0.0f};
#pragma unroll
    for (int seg = 0; seg < 4; ++seg) {
      int4 qv = qrow[seg * 64 + lane];              // 8 bf16 columns
      int c0 = seg * 512 + lane * 8;
      float4 wa = *(const float4*)(wb + c0);
      float4 wc = *(const float4*)(wb + c0 + 4);
      v2f q01 = (v2f){__uint_as_float(((unsigned)qv.x) << 16),
                      __uint_as_float(((unsigned)qv.x) & 0xFFFF0000u)};
      v2f q23 = (v2f){__uint_as_float(((unsigned)qv.y) << 16),
                      __uint_as_float(((unsigned)qv.y) & 0xFFFF0000u)};
      v2f q45 = (v2f){__uint_as_float(((unsigned)qv.z) << 16),
                      __uint_as_float(((unsigned)qv.z) & 0xFFFF0000u)};
      v2f q67 = (v2f){__uint_as_float(((unsigned)qv.w) << 16),
                      __uint_as_float(((unsigned)qv.w) & 0xFFFF0000u)};
      acc += q01 * (v2f){wa.x, wa.y};
      acc += q23 * (v2f){wa.z, wa.w};
      acc += q45 * (v2f){wc.x, wc.y};
      acc += q67 * (v2f){wc.z, wc.w};
    }
    float s = acc.x + acc.y;
#pragma unroll
    for (int off = 1; off < 64; off <<= 1) s += __shfl_xor(s, off);
    if (lane == 0) {
      float c = shift[b * NPTS + n];
      float u = NEG_LOG2N + 0.5f * c - LG2(s);
      outpot[b * NPTS + n] = u;
      outstage[b * NPTS + n] = EX2(u - 0.5f * c);
    }
  }
}

// Exact fp32 half-step (R7-proven). Used for the last v-update + fallback.
__global__ __launch_bounds__(256, 8) void sink_half(
    const float4* __restrict__ Rp, const float4* __restrict__ Cp,
    const float* __restrict__ win, const float* __restrict__ crow,
    float* __restrict__ wout) {
  __shared__ float4 sY[CHUNK];   // 16 KB
  __shared__ float  sv[CHUNK];   // 4 KB
  int bx = blockIdx.x;
  int b = bx >> 7;
  int rblk = bx & 127;
  int tid = threadIdx.x;
  const float4* cb = Cp + b * NPTS;
  const float*  vb = win + b * NPTS;

  int rg = tid >> 5, lane = tid & 31;
  int nbase = rblk * RPB + rg * RPT;

  float4 a0 = Rp[b * NPTS + nbase];
  float4 a1 = Rp[b * NPTS + nbase + 1];
  v2f xx = (v2f){a0.x, a1.x}, xy = (v2f){a0.y, a1.y};
  v2f xz = (v2f){a0.z, a1.z}, xw = (v2f){a0.w, a1.w};
  v2f csh = (v2f){crow[b * NPTS + nbase], crow[b * NPTS + nbase + 1]};
  v2f acc = (v2f){0.0f, 0.0f};
  const v2f sqfloor = (v2f){1e-12f, 1e-12f};

  for (int cch = 0; cch < NPTS / CHUNK; ++cch) {
    if (cch) __syncthreads();
#pragma unroll
    for (int i = 0; i < CHUNK / 256; ++i) {
      sY[tid + i * 256] = cb[cch * CHUNK + tid + i * 256];
      sv[tid + i * 256] = vb[cch * CHUNK + tid + i * 256];
    }
    __syncthreads();

    for (int J = 0; J < CHUNK / (32 * KU); ++J) {
      float4 yp[KU];
      float  vm[KU];
#pragma unroll
      for (int k = 0; k < KU; ++k) {
        int m = J * (32 * KU) + k * 32 + lane;
        yp[k] = sY[m];
        vm[k] = sv[m];
      }
#pragma unroll
      for (int k = 0; k < KU; ++k) {
        v2f dot = xx * yp[k].x;
        dot = xy * yp[k].y + dot;
        dot = xz * yp[k].z + dot;
        v2f sq = xw + yp[k].w;
        sq = dot * (-2.0f) + sq;
        sq = VMAX(sq, sqfloor);
        float d0 = SQRTF(sq.x);
        float d1 = SQRTF(sq.y);
        v2f arg = (v2f){d0, d1} * (-KSCALE) + (csh + vm[k]);
        acc += (v2f){EX2(arg.x), EX2(arg.y)};
      }
    }
  }

  float s0 = acc.x, s1 = acc.y;
#pragma unroll
  for (int off = 1; off < 32; off <<= 1) {
    s0 += __shfl_xor(s0, off);
    s1 += __shfl_xor(s1, off);
  }
  if (lane == 0) {
    wout[b * NPTS + nbase]     = NEG_LOG2N + csh.x - LG2(s0);
    wout[b * NPTS + nbase + 1] = NEG_LOG2N + csh.y - LG2(s1);
  }
}

__global__ __launch_bounds__(256, 4) void final_kernel(
    const float4* __restrict__ Xp, const float4* __restrict__ Yp,
    const float* __restrict__ u2, const float* __restrict__ v2,
    float* __restrict__ partials) {
  __shared__ float4 sY[NPTS];
  __shared__ float  sv[NPTS];
  __shared__ float  red[8];
  int bx = blockIdx.x;
  int b = bx >> 6;
  int rblk = bx & 63;
  int tid = threadIdx.x;
  const float4* cb = Yp + b * NPTS;
  const float*  vb = v2 + b * NPTS;
  for (int i = tid; i < NPTS; i += 256) { sY[i] = cb[i]; sv[i] = vb[i]; }
  __syncthreads();

  int rg = tid >> 5, lane = tid & 31;
  int nbase = rblk * 32 + rg * 4;

  float4 xp[4];
  float un[4], acc[4];
#pragma unroll
  for (int r = 0; r < 4; ++r) {
    xp[r] = Xp[b * NPTS + nbase + r];
    un[r] = u2[b * NPTS + nbase + r];
    acc[r] = 0.0f;
  }

  for (int J = 0; J < NPTS / (32 * KU); ++J) {
    float4 yp[KU];
    float  vm[KU];
#pragma unroll
    for (int k = 0; k < KU; ++k) {
      int m = J * (32 * KU) + k * 32 + lane;
      yp[k] = sY[m];
      vm[k] = sv[m];
    }
#pragma unroll
    for (int k = 0; k < KU; ++k) {
#pragma unroll
      for (int r = 0; r < 4; ++r) {
        float dot = fmaf(xp[r].z, yp[k].z, fmaf(xp[r].y, yp[k].y, xp[r].x * yp[k].x));
        float sq  = fmaf(-2.0f, dot, xp[r].w + yp[k].w);
        float d   = SQRTF(fmaxf(sq, 1e-12f));
        float e   = EX2(fmaf(d, -KSCALE, un[r] + vm[k]));
        acc[r] = fmaf(e, d, acc[r]);
      }
    }
  }
  float a = (acc[0] + acc[1]) + (acc[2] + acc[3]);
#pragma unroll
  for (int off = 1; off < 32; off <<= 1) a += __shfl_xor(a, off);
  if (lane == 0) red[rg] = a;
  __syncthreads();
  if (tid == 0) {
    float sblk = 0.0f;
#pragma unroll
    for (int i = 0; i < 8; ++i) sblk += red[i];
    partials[bx] = sblk;
  }
}

__global__ __launch_bounds__(256) void reduce_kernel(
    const float* __restrict__ partials, float* __restrict__ out) {
  __shared__ float red[4];
  int tid = threadIdx.x;
  float a = (partials[tid] + partials[tid + 256]) +
            (partials[tid + 512] + partials[tid + 768]);
#pragma unroll
  for (int off = 1; off < 64; off <<= 1) a += __shfl_xor(a, off);
  if ((tid & 63) == 0) red[tid >> 6] = a;
  __syncthreads();
  if (tid == 0) out[0] = ((red[0] + red[1]) + (red[2] + red[3])) * (1.0f / BATCH);
}

extern "C" void kernel_launch(void* const* d_in, const int* in_sizes, int n_in,
                              void* d_out, int out_size, void* d_ws, size_t ws_size,
                              hipStream_t stream) {
  const float* tpl = (const float*)d_in[0];
  const float* src = (const float*)d_in[1];
  float* out = (float*)d_out;
  char* ws = (char*)d_ws;

  const size_t ptsBytes = (size_t)BATCH * NPTS * sizeof(float4);   // 512 KB
  const size_t potBytes = (size_t)BATCH * NPTS * sizeof(float);    // 128 KB
  const size_t QBYTES   = (size_t)BATCH * NPTS * NPTS * 2;         // 128 MiB

  float4* Xp = (float4*)ws;
  float4* Yp = (float4*)(ws + ptsBytes);
  float*  u2 = (float*)(ws + 2 * ptsBytes);
  float*  v2 = (float*)(ws + 2 * ptsBytes + potBytes);
  float*  cX = (float*)(ws + 2 * ptsBytes + 2 * potBytes);
  float*  cY = (float*)(ws + 2 * ptsBytes + 3 * potBytes);
  float*  zst = (float*)(ws + 2 * ptsBytes + 4 * potBytes);
  float*  wst = (float*)(ws + 2 * ptsBytes + 5 * potBytes);
  float*  partials = (float*)(ws + 2 * ptsBytes + 6 * potBytes);   // 4 KB
  const size_t smallBytes = 2 * ptsBytes + 6 * potBytes + 4096;
  unsigned short* Q  = (unsigned short*)(ws + smallBytes);
  unsigned short* Qt = (unsigned short*)(ws + smallBytes + QBYTES);
  const bool useQ = ws_size >= smallBytes + 2 * QBYTES;

  prep_kernel<<<(BATCH * NPTS + 255) / 256, 256, 0, stream>>>(tpl, src, Xp, Yp, v2);
  dmin_kernel<<<BATCH * 64, 256, 0, stream>>>(Xp, Yp, cX, zst);  // zst init unused
  dmin_kernel<<<BATCH * 64, 256, 0, stream>>>(Yp, Xp, cY, wst);  // wst = 2^(-cY/2), v=0 stage

  if (useQ) {
    qgen_kernel<<<BATCH * 256, 256, 0, stream>>>(Xp, Yp, cX, cY, Q);
    qgen_kernel<<<BATCH * 256, 256, 0, stream>>>(Yp, Xp, cY, cX, Qt);
    for (int it = 0; it < 50; ++it) {
      gemv_kernel<<<BATCH * 256, 256, 0, stream>>>(Q, wst, cX, u2, zst);
      if (it < 49)
        gemv_kernel<<<BATCH * 256, 256, 0, stream>>>(Qt, zst, cY, v2, wst);
      else  // exact final v-update: fp32-exact column marginals
        sink_half<<<BATCH * 128, 256, 0, stream>>>(Yp, Xp, u2, cY, v2);
    }
  } else {
    for (int it = 0; it < 50; ++it) {
      sink_half<<<BATCH * 128, 256, 0, stream>>>(Xp, Yp, v2, cX, u2);
      sink_half<<<BATCH * 128, 256, 0, stream>>>(Yp, Xp, u2, cY, v2);
    }
  }

  final_kernel<<<BATCH * 64, 256, 0, stream>>>(Xp, Yp, u2, v2, partials);
  reduce_kernel<<<1, 256, 0, stream>>>(partials, out);
}